// Round 1
// baseline (2575.807 us; speedup 1.0000x reference)
//
#include <hip/hip_runtime.h>

#define N_PTS 131072
#define TD 4096
#define DD 64
#define KK 1024
#define CHUNK 64

// ---------------- K1: fp64-exact argmin + fused scatter atomics ----------------
__global__ __launch_bounds__(256, 2) void vq_argmin_scatter(
    const float* __restrict__ z, const float* __restrict__ emb,
    int* __restrict__ idx_ws, float* __restrict__ counts,
    float* __restrict__ esum, float* __restrict__ ind_out)
{
    __shared__ double e_lds[CHUNK][DD];
    __shared__ double enorm_s[CHUNK];
    const int tid = threadIdx.x;
    const int n = blockIdx.x * 256 + tid;
    const int b = n >> 12;
    const int t = n & 4095;
    const float* zb = z + ((size_t)b * DD) * TD + t;

    // z for this point: 64 doubles in VGPRs (exact fp32 values)
    double zr[DD];
#pragma unroll
    for (int d = 0; d < DD; ++d) zr[d] = (double)zb[(size_t)d * TD];

    double best = 1e300;
    int bi = 0;

    for (int c = 0; c < KK / CHUNK; ++c) {
        __syncthreads();
        const int kbase = c * CHUNK;
        // stage chunk of embedding as double
        for (int i = tid; i < CHUNK * DD; i += 256)
            ((double*)e_lds)[i] = (double)emb[kbase * DD + i];
        __syncthreads();
        // per-code squared norms
        if (tid < CHUNK) {
            double s = 0.0;
#pragma unroll
            for (int d = 0; d < DD; ++d) { double e = e_lds[tid][d]; s = fma(e, e, s); }
            enorm_s[tid] = s;
        }
        __syncthreads();
        // scan codes: score = |e|^2 - 2 z.e  (|z|^2 constant per point, drop)
        for (int kk = 0; kk < CHUNK; ++kk) {
            const double2* ep = (const double2*)(&e_lds[kk][0]);
            double a0 = 0.0, a1 = 0.0, a2 = 0.0, a3 = 0.0;
#pragma unroll
            for (int d4 = 0; d4 < DD / 4; ++d4) {
                double2 e01 = ep[2 * d4];
                double2 e23 = ep[2 * d4 + 1];
                a0 = fma(zr[4 * d4 + 0], e01.x, a0);
                a1 = fma(zr[4 * d4 + 1], e01.y, a1);
                a2 = fma(zr[4 * d4 + 2], e23.x, a2);
                a3 = fma(zr[4 * d4 + 3], e23.y, a3);
            }
            double s = enorm_s[kk] - 2.0 * ((a0 + a1) + (a2 + a3));
            if (s < best) { best = s; bi = kbase + kk; }  // strict < keeps first min (numpy argmin)
        }
    }

    idx_ws[n] = bi;
    ind_out[n] = (float)bi;
    atomicAdd(&counts[bi], 1.0f);
    float* row = esum + (size_t)bi * DD;
#pragma unroll
    for (int d = 0; d < DD; ++d) atomicAdd(&row[d], (float)zr[d]);
}

// ---------------- K2: EMA update + Laplace smoothing + new embedding ----------------
__global__ __launch_bounds__(1024) void vq_update(
    const float* __restrict__ cs, const float* __restrict__ counts,
    const float* __restrict__ avg, const float* __restrict__ esum,
    float* __restrict__ newE)
{
    __shared__ double red[1024];
    __shared__ float smo[1024];
    const int k = threadIdx.x;
    const double DECAY = 0.99, OMD = 1.0 - 0.99, EPSV = 1e-5;
    double ncs = DECAY * (double)cs[k] + OMD * (double)counts[k];
    red[k] = ncs;
    __syncthreads();
    for (int s = 512; s > 0; s >>= 1) {
        if (k < s) red[k] += red[k + s];
        __syncthreads();
    }
    double nsum = red[0];
    smo[k] = (float)((ncs + EPSV) / (nsum + (double)KK * EPSV) * nsum);
    __syncthreads();
    for (int it = 0; it < DD; ++it) {
        int j = it * 1024 + k;
        int kk = j >> 6;
        newE[j] = (float)((DECAY * (double)avg[j] + OMD * (double)esum[j]) / (double)smo[kk]);
    }
}

// ---------------- K3: gather z_q + commitment loss ----------------
__global__ __launch_bounds__(256) void vq_gather_loss(
    const float* __restrict__ z, const float* __restrict__ newE,
    const int* __restrict__ idx_ws, float* __restrict__ zq_out,
    double* __restrict__ loss_acc)
{
    const int tid = threadIdx.x;
    const int n = blockIdx.x * 256 + tid;
    const int b = n >> 12;
    const int t = n & 4095;
    const float* zb = z + ((size_t)b * DD) * TD + t;
    float* ob = zq_out + ((size_t)b * DD) * TD + t;
    const int bi = idx_ws[n];
    const float* e = newE + (size_t)bi * DD;
    double acc = 0.0;
#pragma unroll
    for (int d = 0; d < DD; ++d) {
        float q = e[d];
        float zv = zb[(size_t)d * TD];
        ob[(size_t)d * TD] = q;
        float df = zv - q;
        acc = fma((double)df, (double)df, acc);
    }
    for (int off = 32; off > 0; off >>= 1) acc += __shfl_down(acc, off, 64);
    __shared__ double wsum[4];
    const int wid = tid >> 6, lane = tid & 63;
    if (lane == 0) wsum[wid] = acc;
    __syncthreads();
    if (tid == 0) atomicAdd(loss_acc, wsum[0] + wsum[1] + wsum[2] + wsum[3]);
}

// ---------------- K4: finalize loss ----------------
__global__ void vq_finalize(const double* __restrict__ loss_acc, float* __restrict__ loss_out)
{
    *loss_out = (float)(0.25 * (*loss_acc) / (double)(N_PTS * DD));
}

extern "C" void kernel_launch(void* const* d_in, const int* in_sizes, int n_in,
                              void* d_out, int out_size, void* d_ws, size_t ws_size,
                              hipStream_t stream) {
    const float* z    = (const float*)d_in[0];   // [32, 64, 4096]
    const float* emb  = (const float*)d_in[1];   // [1024, 64]
    const float* cs   = (const float*)d_in[2];   // [1024]
    const float* avg  = (const float*)d_in[3];   // [1024, 64]

    float* out      = (float*)d_out;
    float* zq_out   = out;                // 8388608
    float* loss_out = out + 8388608;      // 1
    float* ind_out  = out + 8388609;      // 131072 (indices as float)

    char* ws = (char*)d_ws;
    int*    idx_ws   = (int*)ws;                     // 512 KB
    float*  newE     = (float*)(ws + 524288);        // 256 KB
    float*  counts   = (float*)(ws + 786432);        // 4 KB
    float*  esum     = (float*)(ws + 790528);        // 256 KB
    double* loss_acc = (double*)(ws + 1052672);      // 8 B

    // zero counts + esum + loss_acc (contiguous region)
    hipMemsetAsync(ws + 786432, 0, 4096 + 262144 + 8, stream);

    vq_argmin_scatter<<<N_PTS / 256, 256, 0, stream>>>(z, emb, idx_ws, counts, esum, ind_out);
    vq_update<<<1, 1024, 0, stream>>>(cs, counts, avg, esum, newE);
    vq_gather_loss<<<N_PTS / 256, 256, 0, stream>>>(z, newE, idx_ws, zq_out, loss_acc);
    vq_finalize<<<1, 1, 0, stream>>>(loss_acc, loss_out);
}